// Round 1
// baseline (350.515 us; speedup 1.0000x reference)
//
#include <hip/hip_runtime.h>

// ---------------- constants ----------------
constexpr int kH    = 1024;   // hidden
constexpr int kSEQ  = 2048;
constexpr int kBATCH= 2;
constexpr int kNH   = 16;
constexpr int kHD   = 64;
constexpr int kM    = 4096;   // BATCH*SEQ

typedef _Float16 h8  __attribute__((ext_vector_type(8)));
typedef _Float16 h4  __attribute__((ext_vector_type(4)));
typedef float   f32x4 __attribute__((ext_vector_type(4)));

static __device__ __forceinline__ f32x4 mfma16(h8 a, h8 b, f32x4 c) {
  return __builtin_amdgcn_mfma_f32_16x16x32_f16(a, b, c, 0, 0, 0);
}

// ---------------- fp32 -> fp16 convert ----------------
__global__ __launch_bounds__(256) void cvt_f32_f16(const float* __restrict__ src,
                                                   _Float16* __restrict__ dst, int n4) {
  int i = blockIdx.x * 256 + threadIdx.x;
  if (i < n4) {
    float4 v = reinterpret_cast<const float4*>(src)[i];
    h4 o;
    o[0] = (_Float16)v.x; o[1] = (_Float16)v.y;
    o[2] = (_Float16)v.z; o[3] = (_Float16)v.w;
    reinterpret_cast<h4*>(dst)[i] = o;
  }
}

// ---------------- QKV projection GEMM ----------------
// Y = X @ W^T + b ; X:[4096,1024] fp16, W:[1024,1024] fp16 (row-major [out,in])
// output: head-major [bh][s][d] fp16; proj 0 (Q) pre-scaled by 0.125
__global__ __launch_bounds__(256) void qkv_gemm(
    const _Float16* __restrict__ Xh,
    const _Float16* __restrict__ Wq, const _Float16* __restrict__ Wk,
    const _Float16* __restrict__ Wv,
    const float* __restrict__ bq, const float* __restrict__ bk,
    const float* __restrict__ bv,
    _Float16* __restrict__ Qo, _Float16* __restrict__ Ko, _Float16* __restrict__ Vo)
{
  const int proj = blockIdx.z;
  const _Float16* W   = (proj == 0) ? Wq : ((proj == 1) ? Wk : Wv);
  const float*    bias= (proj == 0) ? bq : ((proj == 1) ? bk : bv);
  _Float16*       Out = (proj == 0) ? Qo : ((proj == 1) ? Ko : Vo);

  const int m0 = blockIdx.y * 64, n0 = blockIdx.x * 64;
  __shared__ __align__(16) _Float16 As[64][40];
  __shared__ __align__(16) _Float16 Bs[64][40];

  const int tid  = threadIdx.x;
  const int wave = tid >> 6, lane = tid & 63, quad = lane >> 4, l16 = lane & 15;
  const int mw = (wave & 1) * 32, nw = (wave >> 1) * 32;

  f32x4 acc[2][2] = {};
  const int sr = tid >> 2, sc = (tid & 3) * 8;
  const _Float16* Asrc = Xh + (size_t)(m0 + sr) * kH + sc;
  const _Float16* Bsrc = W  + (size_t)(n0 + sr) * kH + sc;

  for (int k0 = 0; k0 < kH; k0 += 32) {
    *reinterpret_cast<h8*>(&As[sr][sc]) = *reinterpret_cast<const h8*>(Asrc + k0);
    *reinterpret_cast<h8*>(&Bs[sr][sc]) = *reinterpret_cast<const h8*>(Bsrc + k0);
    __syncthreads();
    h8 a0 = *reinterpret_cast<const h8*>(&As[mw + l16][quad * 8]);
    h8 a1 = *reinterpret_cast<const h8*>(&As[mw + 16 + l16][quad * 8]);
    h8 b0 = *reinterpret_cast<const h8*>(&Bs[nw + l16][quad * 8]);
    h8 b1 = *reinterpret_cast<const h8*>(&Bs[nw + 16 + l16][quad * 8]);
    acc[0][0] = mfma16(a0, b0, acc[0][0]);
    acc[0][1] = mfma16(a0, b1, acc[0][1]);
    acc[1][0] = mfma16(a1, b0, acc[1][0]);
    acc[1][1] = mfma16(a1, b1, acc[1][1]);
    __syncthreads();
  }

  #pragma unroll
  for (int mi = 0; mi < 2; ++mi)
  #pragma unroll
  for (int ni = 0; ni < 2; ++ni) {
    const int ng = n0 + nw + ni * 16 + l16;
    const float bv_ = bias[ng];
    #pragma unroll
    for (int r = 0; r < 4; ++r) {
      const int mg = m0 + mw + mi * 16 + quad * 4 + r;
      float val = acc[mi][ni][r] + bv_;
      if (proj == 0) val *= 0.125f;                 // 1/sqrt(64), exact in fp16
      const int bb = mg >> 11, srow = mg & 2047;    // batch, seq
      const int hh = ng >> 6,  dd   = ng & 63;      // head, dim
      Out[(((size_t)(bb * kNH + hh) * kSEQ) + srow) * kHD + dd] = (_Float16)val;
    }
  }
}

// ---------------- flash attention ----------------
// per block: one (bh), one 64-row q tile. wave w owns q rows [w*16, w*16+16)
__global__ __launch_bounds__(256) void attn_kernel(
    const _Float16* __restrict__ Q, const _Float16* __restrict__ K,
    const _Float16* __restrict__ V, _Float16* __restrict__ Ctx)
{
  const int qt = blockIdx.x;
  const int bh = blockIdx.y;
  const int tid = threadIdx.x;
  const int wave = tid >> 6, lane = tid & 63, quad = lane >> 4, l16 = lane & 15;

  __shared__ __align__(16) _Float16 Vt[64][72];      // V tile transposed: [d][key]
  __shared__ __align__(16) _Float16 Pl[4][16][72];   // per-wave P round-trip

  const _Float16* Qb = Q + (size_t)bh * kSEQ * kHD;
  const _Float16* Kb = K + (size_t)bh * kSEQ * kHD;
  const _Float16* Vb = V + (size_t)bh * kSEQ * kHD;

  const int qrow = qt * 64 + wave * 16 + l16;
  h8 qf0 = *reinterpret_cast<const h8*>(&Qb[(size_t)qrow * kHD + quad * 8]);
  h8 qf1 = *reinterpret_cast<const h8*>(&Qb[(size_t)qrow * kHD + 32 + quad * 8]);

  float m_i[4], l_i[4];
  f32x4 o[4] = {};
  #pragma unroll
  for (int r = 0; r < 4; ++r) { m_i[r] = -1e30f; l_i[r] = 0.f; }

  for (int kt = 0; kt < kSEQ / 64; ++kt) {
    // stage V tile transposed: wave w handles d range [w*16, w*16+16), lane = key
    {
      const _Float16* vsrc = &Vb[(size_t)(kt * 64 + lane) * kHD + wave * 16];
      h8 p0 = *reinterpret_cast<const h8*>(vsrc);
      h8 p1 = *reinterpret_cast<const h8*>(vsrc + 8);
      #pragma unroll
      for (int e = 0; e < 8; ++e) Vt[wave * 16 + e][lane] = p0[e];
      #pragma unroll
      for (int e = 0; e < 8; ++e) Vt[wave * 16 + 8 + e][lane] = p1[e];
    }
    // scores S = Q' K^T   (Q pre-scaled)
    f32x4 s[4];
    #pragma unroll
    for (int nt = 0; nt < 4; ++nt) {
      const _Float16* kr = &Kb[(size_t)(kt * 64 + nt * 16 + l16) * kHD];
      h8 b0 = *reinterpret_cast<const h8*>(kr + quad * 8);
      h8 b1 = *reinterpret_cast<const h8*>(kr + 32 + quad * 8);
      f32x4 a = {};
      a = mfma16(qf0, b0, a);
      a = mfma16(qf1, b1, a);
      s[nt] = a;
    }
    // online softmax (rows = quad*4+r, replicated across the 16 lanes of a quad)
    float vmax[4];
    #pragma unroll
    for (int r = 0; r < 4; ++r)
      vmax[r] = fmaxf(fmaxf(s[0][r], s[1][r]), fmaxf(s[2][r], s[3][r]));
    #pragma unroll
    for (int off = 1; off < 16; off <<= 1)
      #pragma unroll
      for (int r = 0; r < 4; ++r)
        vmax[r] = fmaxf(vmax[r], __shfl_xor(vmax[r], off));
    float alpha[4], rs[4];
    #pragma unroll
    for (int r = 0; r < 4; ++r) {
      float mn = fmaxf(m_i[r], vmax[r]);
      alpha[r] = __expf(m_i[r] - mn);
      m_i[r] = mn;
      rs[r] = 0.f;
    }
    #pragma unroll
    for (int nt = 0; nt < 4; ++nt)
      #pragma unroll
      for (int r = 0; r < 4; ++r) {
        float p = __expf(s[nt][r] - m_i[r]);
        s[nt][r] = p;
        rs[r] += p;
      }
    #pragma unroll
    for (int off = 1; off < 16; off <<= 1)
      #pragma unroll
      for (int r = 0; r < 4; ++r)
        rs[r] += __shfl_xor(rs[r], off);
    #pragma unroll
    for (int r = 0; r < 4; ++r) l_i[r] = l_i[r] * alpha[r] + rs[r];
    #pragma unroll
    for (int nt = 0; nt < 4; ++nt)
      #pragma unroll
      for (int r = 0; r < 4; ++r) o[nt][r] *= alpha[r];
    // P: C-layout regs -> LDS -> A-layout
    #pragma unroll
    for (int nt = 0; nt < 4; ++nt)
      #pragma unroll
      for (int r = 0; r < 4; ++r)
        Pl[wave][quad * 4 + r][nt * 16 + l16] = (_Float16)s[nt][r];
    __syncthreads();   // Vt staged by all waves + own P writes drained
    h8 pf0 = *reinterpret_cast<const h8*>(&Pl[wave][l16][quad * 8]);
    h8 pf1 = *reinterpret_cast<const h8*>(&Pl[wave][l16][32 + quad * 8]);
    #pragma unroll
    for (int nt = 0; nt < 4; ++nt) {
      h8 v0 = *reinterpret_cast<const h8*>(&Vt[nt * 16 + l16][quad * 8]);
      h8 v1 = *reinterpret_cast<const h8*>(&Vt[nt * 16 + l16][32 + quad * 8]);
      o[nt] = mfma16(pf0, v0, o[nt]);
      o[nt] = mfma16(pf1, v1, o[nt]);
    }
    __syncthreads();   // protect Vt before next iteration's staging
  }
  // epilogue: ctx[b][s][h*64+d] fp16
  const int b = bh >> 4, hh = bh & 15;
  #pragma unroll
  for (int nt = 0; nt < 4; ++nt)
    #pragma unroll
    for (int r = 0; r < 4; ++r) {
      float val = o[nt][r] / l_i[r];
      const int srow = qt * 64 + wave * 16 + quad * 4 + r;
      const int col  = hh * kHD + nt * 16 + l16;
      Ctx[((size_t)(b * kSEQ + srow)) * kH + col] = (_Float16)val;
    }
}

// ---------------- output dense + bias + residual ----------------
__global__ __launch_bounds__(256) void dense_gemm(
    const _Float16* __restrict__ A, const _Float16* __restrict__ W,
    const float* __restrict__ bias, const float* __restrict__ resid,
    float* __restrict__ Out)
{
  const int m0 = blockIdx.y * 64, n0 = blockIdx.x * 64;
  __shared__ __align__(16) _Float16 As[64][40];
  __shared__ __align__(16) _Float16 Bs[64][40];
  const int tid  = threadIdx.x;
  const int wave = tid >> 6, lane = tid & 63, quad = lane >> 4, l16 = lane & 15;
  const int mw = (wave & 1) * 32, nw = (wave >> 1) * 32;
  f32x4 acc[2][2] = {};
  const int sr = tid >> 2, sc = (tid & 3) * 8;
  const _Float16* Asrc = A + (size_t)(m0 + sr) * kH + sc;
  const _Float16* Bsrc = W + (size_t)(n0 + sr) * kH + sc;
  for (int k0 = 0; k0 < kH; k0 += 32) {
    *reinterpret_cast<h8*>(&As[sr][sc]) = *reinterpret_cast<const h8*>(Asrc + k0);
    *reinterpret_cast<h8*>(&Bs[sr][sc]) = *reinterpret_cast<const h8*>(Bsrc + k0);
    __syncthreads();
    h8 a0 = *reinterpret_cast<const h8*>(&As[mw + l16][quad * 8]);
    h8 a1 = *reinterpret_cast<const h8*>(&As[mw + 16 + l16][quad * 8]);
    h8 b0 = *reinterpret_cast<const h8*>(&Bs[nw + l16][quad * 8]);
    h8 b1 = *reinterpret_cast<const h8*>(&Bs[nw + 16 + l16][quad * 8]);
    acc[0][0] = mfma16(a0, b0, acc[0][0]);
    acc[0][1] = mfma16(a0, b1, acc[0][1]);
    acc[1][0] = mfma16(a1, b0, acc[1][0]);
    acc[1][1] = mfma16(a1, b1, acc[1][1]);
    __syncthreads();
  }
  #pragma unroll
  for (int mi = 0; mi < 2; ++mi)
  #pragma unroll
  for (int ni = 0; ni < 2; ++ni) {
    const int ng = n0 + nw + ni * 16 + l16;
    const float bv_ = bias[ng];
    #pragma unroll
    for (int r = 0; r < 4; ++r) {
      const int mg = m0 + mw + mi * 16 + quad * 4 + r;
      Out[(size_t)mg * kH + ng] = acc[mi][ni][r] + bv_ + resid[(size_t)mg * kH + ng];
    }
  }
}

// ---------------- LayerNorm ----------------
__global__ __launch_bounds__(256) void ln_kernel(const float* __restrict__ Tmp,
    const float* __restrict__ gamma, const float* __restrict__ beta,
    float* __restrict__ out)
{
  const int row = blockIdx.x;
  const float4 v = reinterpret_cast<const float4*>(Tmp + (size_t)row * kH)[threadIdx.x];
  float s  = v.x + v.y + v.z + v.w;
  float ss = v.x * v.x + v.y * v.y + v.z * v.z + v.w * v.w;
  #pragma unroll
  for (int off = 32; off > 0; off >>= 1) {
    s  += __shfl_down(s, off);
    ss += __shfl_down(ss, off);
  }
  __shared__ float red[8];
  const int wave = threadIdx.x >> 6, lane = threadIdx.x & 63;
  if (lane == 0) { red[wave] = s; red[4 + wave] = ss; }
  __syncthreads();
  s  = red[0] + red[1] + red[2] + red[3];
  ss = red[4] + red[5] + red[6] + red[7];
  const float mu   = s * (1.f / kH);
  const float var  = ss * (1.f / kH) - mu * mu;
  const float rstd = rsqrtf(var + 1e-5f);
  const float4 g  = reinterpret_cast<const float4*>(gamma)[threadIdx.x];
  const float4 bb = reinterpret_cast<const float4*>(beta)[threadIdx.x];
  float4 o;
  o.x = (v.x - mu) * rstd * g.x + bb.x;
  o.y = (v.y - mu) * rstd * g.y + bb.y;
  o.z = (v.z - mu) * rstd * g.z + bb.z;
  o.w = (v.w - mu) * rstd * g.w + bb.w;
  reinterpret_cast<float4*>(out + (size_t)row * kH)[threadIdx.x] = o;
}

// ---------------- launch ----------------
extern "C" void kernel_launch(void* const* d_in, const int* in_sizes, int n_in,
                              void* d_out, int out_size, void* d_ws, size_t ws_size,
                              hipStream_t stream) {
  const float* hs    = (const float*)d_in[0];
  const float* Wq    = (const float*)d_in[1];
  const float* bq    = (const float*)d_in[2];
  const float* Wk    = (const float*)d_in[3];
  const float* bk    = (const float*)d_in[4];
  const float* Wv    = (const float*)d_in[5];
  const float* bv    = (const float*)d_in[6];
  const float* Wd    = (const float*)d_in[7];
  const float* bd    = (const float*)d_in[8];
  const float* gamma = (const float*)d_in[9];
  const float* beta  = (const float*)d_in[10];
  float* out = (float*)d_out;

  char* ws = (char*)d_ws;
  _Float16* Xh  = (_Float16*)(ws + 0);          //  8 MiB  [4096][1024]
  _Float16* Wqh = (_Float16*)(ws + 8388608);    //  2 MiB
  _Float16* Wkh = (_Float16*)(ws + 10485760);   //  2 MiB
  _Float16* Wvh = (_Float16*)(ws + 12582912);   //  2 MiB
  _Float16* Wdh = (_Float16*)(ws + 14680064);   //  2 MiB
  _Float16* Qh  = (_Float16*)(ws + 16777216);   //  8 MiB  [32][2048][64]
  _Float16* Kh  = (_Float16*)(ws + 25165824);   //  8 MiB
  _Float16* Vh  = (_Float16*)(ws + 33554432);   //  8 MiB
  _Float16* Ch  = (_Float16*)(ws + 41943040);   //  8 MiB  [4096][1024]
  float*    Tmp = (float*)   (ws + 50331648);   // 16 MiB  [4096][1024]  (total 64 MiB)

  cvt_f32_f16<<<4096, 256, 0, stream>>>(hs, Xh, (kM * kH) / 4);
  cvt_f32_f16<<<1024, 256, 0, stream>>>(Wq, Wqh, (kH * kH) / 4);
  cvt_f32_f16<<<1024, 256, 0, stream>>>(Wk, Wkh, (kH * kH) / 4);
  cvt_f32_f16<<<1024, 256, 0, stream>>>(Wv, Wvh, (kH * kH) / 4);
  cvt_f32_f16<<<1024, 256, 0, stream>>>(Wd, Wdh, (kH * kH) / 4);

  qkv_gemm<<<dim3(kH / 64, kM / 64, 3), 256, 0, stream>>>(
      Xh, Wqh, Wkh, Wvh, bq, bk, bv, Qh, Kh, Vh);
  attn_kernel<<<dim3(kSEQ / 64, kBATCH * kNH), 256, 0, stream>>>(Qh, Kh, Vh, Ch);
  dense_gemm<<<dim3(kH / 64, kM / 64), 256, 0, stream>>>(Ch, Wdh, bd, hs, Tmp);
  ln_kernel<<<kM, 256, 0, stream>>>(Tmp, gamma, beta, out);
}